// Round 1
// baseline (43978.119 us; speedup 1.0000x reference)
//
#include <hip/hip_runtime.h>

#define GD 256   // grid (workgroups) -- must be <= CU count for residency
#define BD 256   // block

constexpr int BB = 32;      // batch
constexpr int TSTEPS = 256; // sequence length
constexpr int DD = 512;     // d_in = d_out = d_ctx = a_hid
constexpr int KK4 = 2048;   // 4*D_OUT
constexpr int LC = 128;     // context length

// ---- workspace layout (float offsets) ----
constexpr size_t OFF_H    = 0;                   // [32][512] row-major
constexpr size_t OFF_C    = OFF_H    + 16384;    // [32][512]
constexpr size_t OFF_HATT = OFF_C    + 16384;    // [32][512] row-major
constexpr size_t OFF_HU   = OFF_HATT + 16384;    // [2048][32] col-major
constexpr size_t OFF_XW   = OFF_HU   + 65536;    // 2 x [2048][32] col-major (double buffer)
constexpr size_t OFF_WCTX = OFF_XW   + 131072;   // [32][512] unnormalized, atomics
constexpr size_t OFF_Z    = OFF_WCTX + 16384;    // [32] (+pad)
constexpr size_t OFF_ATT  = OFF_Z    + 64;       // [32*128][512]  context @ W_ctx_att + b_att
constexpr size_t OFF_BAR  = OFF_ATT  + 2097152;  // barrier ints
constexpr size_t WS_FLOATS = OFF_BAR + 64;

__device__ __forceinline__ float rcp_fast(float x) { return __builtin_amdgcn_rcpf(x); }
__device__ __forceinline__ float ftanh(float x) {
  float e = __expf(2.0f * x);                  // saturates correctly at +-inf
  return 1.0f - 2.0f * rcp_fast(e + 1.0f);
}
__device__ __forceinline__ float fsig(float x) {
  return rcp_fast(1.0f + __expf(-x));
}

// grid-wide barrier: release(fence)+agent-add, spin agent-load, acquire(fence).
__device__ __forceinline__ void gsync(int* bar, int& gen) {
  __syncthreads();
  if (threadIdx.x == 0) {
    gen++;
    __threadfence();   // agent-scope release: wbl2 so other XCDs see our stores
    __hip_atomic_fetch_add(bar, 1, __ATOMIC_RELAXED, __HIP_MEMORY_SCOPE_AGENT);
    const int target = gen * GD;
    while (__hip_atomic_load(bar, __ATOMIC_RELAXED, __HIP_MEMORY_SCOPE_AGENT) < target)
      __builtin_amdgcn_s_sleep(4);
    __threadfence();   // agent-scope acquire: invalidate L1/L2 before reading peers' data
  }
  __syncthreads();
}

// Stage 32 rows x 512 cols (row stride rstride) into LDS, transposed + XOR-swizzled.
// Element (k,b) lives at buf[k*32 + (b ^ ((k>>2)&31))]  -> conflict-free writes & reads.
__device__ __forceinline__ void stage_rows(float* buf, const float* __restrict__ src,
                                           size_t rstride) {
  const int t = threadIdx.x;
  for (int i = 0; i < 16; i++) {
    int idx4 = i * BD + t;            // 4096 float4s total
    int b = idx4 >> 7, k4 = idx4 & 127;
    float4 v = *(const float4*)(src + (size_t)b * rstride + (size_t)(k4 * 4));
    int bw = b ^ (k4 & 31);
    int base = k4 * 128;              // (k4*4)*32
    buf[base      + bw] = v.x;
    buf[base + 32 + bw] = v.y;
    buf[base + 64 + bw] = v.z;
    buf[base + 96 + bw] = v.w;
  }
}

__device__ __forceinline__ float lds_at(const float* buf, int k, int b) {
  return buf[k * 32 + (b ^ ((k >> 2) & 31))];
}

// 16-col skinny GEMM: out[32 x 16] = staged[32 x 512] * M[:, cb:cb+16]
__device__ __forceinline__ void gemm16(const float* buf, const float* __restrict__ M,
                                       int N, int cb, float* acc) {
  const int t = threadIdx.x, b = t & 31, s = t >> 5, k0 = s * 64;
  for (int k = k0; k < k0 + 64; k++) {
    float hv = lds_at(buf, k, b);
    const float* row = M + (size_t)k * N + cb;
#pragma unroll
    for (int cc = 0; cc < 16; cc += 4) {
      float4 wv = *(const float4*)(row + cc);
      acc[cc]   += hv * wv.x; acc[cc+1] += hv * wv.y;
      acc[cc+2] += hv * wv.z; acc[cc+3] += hv * wv.w;
    }
  }
}

// reduce 8 k-slices and write 32x16 outputs: dst[b*rstride + (cb+c)*cstride]
__device__ __forceinline__ void reduce_write16(float* buf, const float* acc, float* dst,
                                               size_t rstride, size_t cstride, int cb) {
  const int t = threadIdx.x, b = t & 31, s = t >> 5;
  __syncthreads();                       // staged source dead
#pragma unroll
  for (int cc = 0; cc < 16; cc++) buf[(cc * 8 + s) * 32 + b] = acc[cc];
  __syncthreads();
  for (int o = t; o < 512; o += BD) {
    int b2 = o & 31, c2 = o >> 5;
    float sum = 0.f;
#pragma unroll
    for (int s2 = 0; s2 < 8; s2++) sum += buf[(c2 * 8 + s2) * 32 + b2];
    dst[(size_t)b2 * rstride + (size_t)(cb + c2) * cstride] = sum;
  }
}

// xw[tt] = x[:, tt, :] @ W  for this WG's 8 columns; dst col-major [col][32]
__device__ __forceinline__ void xw_stage_compute(float* buf, const float* __restrict__ x,
                                                 const float* __restrict__ W,
                                                 float* __restrict__ xw, int tt) {
  const int t = threadIdx.x;
  __syncthreads();                       // previous buf users done
  stage_rows(buf, x + (size_t)tt * DD, (size_t)TSTEPS * DD);
  __syncthreads();
  const int b = t & 31, s = t >> 5, k0 = s * 64;
  const int cb = blockIdx.x * 8;
  float acc[8] = {0.f,0.f,0.f,0.f,0.f,0.f,0.f,0.f};
  for (int k = k0; k < k0 + 64; k++) {
    float hv = lds_at(buf, k, b);
    const float* row = W + (size_t)k * KK4 + cb;
    float4 w0 = *(const float4*)(row);
    float4 w1 = *(const float4*)(row + 4);
    acc[0] += hv * w0.x; acc[1] += hv * w0.y; acc[2] += hv * w0.z; acc[3] += hv * w0.w;
    acc[4] += hv * w1.x; acc[5] += hv * w1.y; acc[6] += hv * w1.z; acc[7] += hv * w1.w;
  }
  __syncthreads();
#pragma unroll
  for (int cc = 0; cc < 8; cc++) buf[(cc * 8 + s) * 32 + b] = acc[cc];
  __syncthreads();
  const int b2 = t & 31, c2 = t >> 5;
  float sum = 0.f;
#pragma unroll
  for (int s2 = 0; s2 < 8; s2++) sum += buf[(c2 * 8 + s2) * 32 + b2];
  float* dst = xw + (size_t)(tt & 1) * 65536;
  dst[(size_t)(cb + c2) * 32 + b2] = sum;   // coalesced (b2 fastest)
}

__global__ __launch_bounds__(BD, 1) void attn_lstm_persistent(
    const float* __restrict__ x, const float* __restrict__ ctx,
    const float* __restrict__ W, const float* __restrict__ V,
    const float* __restrict__ U, const float* __restrict__ bias,
    const float* __restrict__ Wh, const float* __restrict__ Wc,
    const float* __restrict__ batt, const float* __restrict__ wprj,
    float* __restrict__ out, float* __restrict__ ws) {
  __shared__ float buf[16384];           // 64 KB
  const int w = blockIdx.x;
  const int t = threadIdx.x;
  float* h    = ws + OFF_H;
  float* c    = ws + OFF_C;
  float* hatt = ws + OFF_HATT;
  float* hU   = ws + OFF_HU;
  float* xw   = ws + OFF_XW;
  float* wctx = ws + OFF_WCTX;
  float* Z    = ws + OFF_Z;
  float* att  = ws + OFF_ATT;
  int*   bar  = (int*)(ws + OFF_BAR);
  int gen = 0;

  // ---------------- setup: att_ctx = context @ Wc + b_att ----------------
  {
    const int r0 = w * 16;               // 16 of 4096 (b,l) rows per WG
    for (int i = 0; i < 8; i++) {        // stage 16 rows of context
      int idx4 = i * BD + t;
      int row = idx4 >> 7, c4 = idx4 & 127;
      ((float4*)buf)[idx4] = ((const float4*)(ctx + (size_t)(r0 + row) * DD))[c4];
    }
    __syncthreads();
    float accA[16], accB[16];
#pragma unroll
    for (int r = 0; r < 16; r++) { accA[r] = 0.f; accB[r] = 0.f; }
    const int a0 = t, a1 = t + 256;
    for (int cc = 0; cc < DD; cc++) {
      float w0 = Wc[(size_t)cc * DD + a0];
      float w1 = Wc[(size_t)cc * DD + a1];
#pragma unroll
      for (int r = 0; r < 16; r++) {
        float cv = buf[r * DD + cc];     // LDS broadcast
        accA[r] += cv * w0; accB[r] += cv * w1;
      }
    }
    const float ba0 = batt[a0], ba1 = batt[a1];
    for (int r = 0; r < 16; r++) {
      att[(size_t)(r0 + r) * DD + a0] = accA[r] + ba0;
      att[(size_t)(r0 + r) * DD + a1] = accB[r] + ba1;
    }
  }
  xw_stage_compute(buf, x, W, xw, 0);    // xw for t=0 into parity-0 buffer
  gsync(bar, gen);

  // ---------------- recurrence ----------------
  for (int step = 0; step < TSTEPS; step++) {
    // ---- S1: h_att = h@Wh (WGs 0-31), hU = h@U (WGs 32-159); rest zero wctx/Z ----
    if (w < 160) {
      stage_rows(buf, h, DD);
      __syncthreads();
      float acc[16];
#pragma unroll
      for (int i = 0; i < 16; i++) acc[i] = 0.f;
      if (w < 32) {
        const int cb = w * 16;
        gemm16(buf, Wh, DD, cb, acc);
        reduce_write16(buf, acc, hatt, DD, 1, cb);      // row-major
      } else {
        const int cb = (w - 32) * 16;
        gemm16(buf, U, KK4, cb, acc);
        reduce_write16(buf, acc, hU, 1, 32, cb);        // col-major [col][32]
      }
    } else {
      for (int i = (w - 160) * BD + t; i < 16384 + 64; i += 96 * BD)
        wctx[i] = 0.f;                    // zeroes wctx then contiguous Z
    }
    gsync(bar, gen);

    // ---- S2: attention scores + unnormalized wctx partials; prefetch xw[t+1] ----
    {
      const int b = w >> 3, l0 = (w & 7) * 16;
      const int l = t >> 4, u = t & 15;
      const float* ar = att + (size_t)(b * LC + l0 + l) * DD;
      const float* hr = hatt + (size_t)b * DD;
      float p = 0.f;
#pragma unroll
      for (int j = 0; j < 8; j++) {
        int a4 = j * 16 + u;
        float4 av = ((const float4*)ar)[a4];
        float4 hv = ((const float4*)hr)[a4];
        float4 wv = ((const float4*)wprj)[a4];
        p += ftanh(av.x + hv.x) * wv.x + ftanh(av.y + hv.y) * wv.y
           + ftanh(av.z + hv.z) * wv.z + ftanh(av.w + hv.w) * wv.w;
      }
      p += __shfl_xor(p, 8); p += __shfl_xor(p, 4);
      p += __shfl_xor(p, 2); p += __shfl_xor(p, 1);
      if (u == 0) {
        float uv = __expf(p);             // |p| <~ 3-5: no max-subtraction needed
        buf[l] = uv;
        atomicAdd(&Z[b], uv);
      }
      __syncthreads();
      float s0 = 0.f, s1 = 0.f;
      const float* cr = ctx + (size_t)(b * LC + l0) * DD;
#pragma unroll 4
      for (int l2 = 0; l2 < 16; l2++) {
        float uv = buf[l2];
        s0 += uv * cr[l2 * DD + t];
        s1 += uv * cr[l2 * DD + t + 256];
      }
      atomicAdd(&wctx[(size_t)b * DD + t], s0);
      atomicAdd(&wctx[(size_t)b * DD + t + 256], s1);
      if (step + 1 < TSTEPS) xw_stage_compute(buf, x, W, xw, step + 1);
    }
    gsync(bar, gen);

    // ---- S3: preact = xw + hU + wctx@V + bias; gates; h/c update ----
    {
      // stage wctx normalized by Z, transposed+swizzled
      for (int i = 0; i < 16; i++) {
        int idx4 = i * BD + t;
        int b = idx4 >> 7, k4 = idx4 & 127;
        float4 v = ((const float4*)(wctx + (size_t)b * DD))[k4];
        float rz = rcp_fast(Z[b]);
        int bw = b ^ (k4 & 31);
        int base = k4 * 128;
        buf[base      + bw] = v.x * rz;
        buf[base + 32 + bw] = v.y * rz;
        buf[base + 64 + bw] = v.z * rz;
        buf[base + 96 + bw] = v.w * rz;
      }
      __syncthreads();
      const int b = t & 31, s = t >> 5, k0 = s * 64;
      const int d0 = w * 2;
      float acc[8] = {0.f,0.f,0.f,0.f,0.f,0.f,0.f,0.f};
      for (int k = k0; k < k0 + 64; k++) {
        float wv = lds_at(buf, k, b);
        const float* row = V + (size_t)k * KK4 + d0;
        float2 g0 = *(const float2*)(row);
        float2 g1 = *(const float2*)(row + 512);
        float2 g2 = *(const float2*)(row + 1024);
        float2 g3 = *(const float2*)(row + 1536);
        acc[0] += wv * g0.x; acc[1] += wv * g0.y;
        acc[2] += wv * g1.x; acc[3] += wv * g1.y;
        acc[4] += wv * g2.x; acc[5] += wv * g2.y;
        acc[6] += wv * g3.x; acc[7] += wv * g3.y;
      }
      __syncthreads();
#pragma unroll
      for (int cc = 0; cc < 8; cc++) buf[(cc * 8 + s) * 32 + b] = acc[cc];
      __syncthreads();
      {
        const int b2 = t & 31, c2 = t >> 5;       // c2 = gate*2 + dd
        float sum = 0.f;
#pragma unroll
        for (int s2 = 0; s2 < 8; s2++) sum += buf[(c2 * 8 + s2) * 32 + b2];
        const int col = d0 + (c2 & 1) + (c2 >> 1) * 512;
        const float* xwc = xw + (size_t)(step & 1) * 65536;
        sum += xwc[(size_t)col * 32 + b2] + hU[(size_t)col * 32 + b2] + bias[col];
        buf[2048 + c2 * 32 + b2] = sum;           // disjoint from partials region
      }
      __syncthreads();
      if (t < 64) {
        const int b3 = t & 31, dd = t >> 5;
        const int d = d0 + dd;
        float pi = buf[2048 + (0 + dd) * 32 + b3];
        float pf = buf[2048 + (2 + dd) * 32 + b3];
        float po = buf[2048 + (4 + dd) * 32 + b3];
        float pg = buf[2048 + (6 + dd) * 32 + b3];
        float ig = fsig(pi), fg = fsig(pf), og = fsig(po), gg = ftanh(pg);
        const size_t off = (size_t)b3 * DD + d;
        float cn = fg * c[off] + ig * gg;
        c[off] = cn;
        float hn = og * ftanh(cn);
        h[off] = hn;
        out[(size_t)b3 * (TSTEPS * DD) + (size_t)step * DD + d] = hn;
      }
    }
    gsync(bar, gen);
  }
}

extern "C" void kernel_launch(void* const* d_in, const int* in_sizes, int n_in,
                              void* d_out, int out_size, void* d_ws, size_t ws_size,
                              hipStream_t stream) {
  (void)in_sizes; (void)n_in; (void)out_size; (void)ws_size;
  const float* x    = (const float*)d_in[0];
  const float* ctx  = (const float*)d_in[1];
  const float* W    = (const float*)d_in[2];
  const float* V    = (const float*)d_in[3];
  const float* U    = (const float*)d_in[4];
  const float* b    = (const float*)d_in[5];
  const float* Wh   = (const float*)d_in[6];
  const float* Wc   = (const float*)d_in[7];
  const float* batt = (const float*)d_in[8];
  const float* wprj = (const float*)d_in[9];

  // zero h and c (first 32768 floats) and the barrier counter
  hipMemsetAsync(d_ws, 0, 32768 * sizeof(float), stream);
  hipMemsetAsync((char*)d_ws + OFF_BAR * sizeof(float), 0, 64 * sizeof(int), stream);

  hipLaunchKernelGGL(attn_lstm_persistent, dim3(GD), dim3(BD), 0, stream,
                     x, ctx, W, V, U, b, Wh, Wc, batt, wprj,
                     (float*)d_out, (float*)d_ws);
}

// Round 2
// 16791.731 us; speedup vs baseline: 2.6190x; 2.6190x over previous
//
#include <hip/hip_runtime.h>

#define GD 256   // grid (workgroups) -- must be <= CU count for residency
#define BD 256   // block

constexpr int TSTEPS = 256; // sequence length
constexpr int DD = 512;     // d_in = d_out = d_ctx = a_hid
constexpr int KK4 = 2048;   // 4*D_OUT
constexpr int LC = 128;     // context length

// ---- workspace layout (float offsets) ----
constexpr size_t OFF_H    = 0;                   // [32][512] row-major (coherent)
constexpr size_t OFF_HATT = OFF_H    + 16384;    // [32][512] row-major (coherent)
constexpr size_t OFF_WCTX = OFF_HATT + 16384;    // [32][512] unnormalized (atomics)
constexpr size_t OFF_Z    = OFF_WCTX + 16384;    // [32] (+pad)
constexpr size_t OFF_BAR  = OFF_Z    + 64;       // barrier ints
constexpr size_t OFF_ATT  = OFF_BAR  + 64;       // [32*128][512] context@Wc + b_att (WG-local)

__device__ __forceinline__ float rcp_fast(float x) { return __builtin_amdgcn_rcpf(x); }
__device__ __forceinline__ float ftanh(float x) {
  float e = __expf(2.0f * x);
  return 1.0f - 2.0f * rcp_fast(e + 1.0f);
}
__device__ __forceinline__ float fsig(float x) { return rcp_fast(1.0f + __expf(-x)); }

// coherent (agent-scope, L2-bypassing) scalar access -- does NOT invalidate L2
__device__ __forceinline__ float cload(const float* p) {
  return __hip_atomic_load(p, __ATOMIC_RELAXED, __HIP_MEMORY_SCOPE_AGENT);
}
__device__ __forceinline__ void cstore(float* p, float v) {
  __hip_atomic_store(p, v, __ATOMIC_RELAXED, __HIP_MEMORY_SCOPE_AGENT);
}

// grid barrier: __syncthreads drains each wave's vmcnt (stores visible at MALL
// since all cross-WG stores are sc-coherent); relaxed agent add + spin; NO cache
// invalidation (readers use coherent loads).
__device__ __forceinline__ void gsync(int* bar, int& gen) {
  __syncthreads();
  if (threadIdx.x == 0) {
    gen++;
    __hip_atomic_fetch_add(bar, 1, __ATOMIC_RELAXED, __HIP_MEMORY_SCOPE_AGENT);
    const int target = gen * GD;
    while (__hip_atomic_load(bar, __ATOMIC_RELAXED, __HIP_MEMORY_SCOPE_AGENT) < target)
      __builtin_amdgcn_s_sleep(2);
    asm volatile("" ::: "memory");
  }
  __syncthreads();
}

// Stage 32 rows x 512 cols into LDS transposed + XOR-swizzled, NORMAL loads.
// (k,b) -> buf[k*32 + (b ^ ((k>>2)&31))]
__device__ __forceinline__ void stage_rows(float* buf, const float* __restrict__ src,
                                           size_t rstride) {
  const int t = threadIdx.x;
#pragma unroll 4
  for (int i = 0; i < 16; i++) {
    int idx4 = i * BD + t;
    int b = idx4 >> 7, k4 = idx4 & 127;
    float4 v = *(const float4*)(src + (size_t)b * rstride + (size_t)(k4 * 4));
    int bw = b ^ (k4 & 31);
    int base = k4 * 128;
    buf[base      + bw] = v.x;
    buf[base + 32 + bw] = v.y;
    buf[base + 64 + bw] = v.z;
    buf[base + 96 + bw] = v.w;
  }
}

// Same staging but with coherent loads, batched 32-deep for latency pipelining.
__device__ __forceinline__ void stage_rows_coh(float* buf, const float* src) {
  const int t = threadIdx.x;
#pragma unroll
  for (int half = 0; half < 2; half++) {
    float v[32];
#pragma unroll
    for (int i = 0; i < 8; i++) {
      int idx4 = (half * 8 + i) * BD + t;
      int b = idx4 >> 7, k4 = idx4 & 127;
      const float* p = src + (size_t)b * DD + (size_t)(k4 * 4);
      v[i*4+0] = cload(p);     v[i*4+1] = cload(p + 1);
      v[i*4+2] = cload(p + 2); v[i*4+3] = cload(p + 3);
    }
#pragma unroll
    for (int i = 0; i < 8; i++) {
      int idx4 = (half * 8 + i) * BD + t;
      int b = idx4 >> 7, k4 = idx4 & 127;
      int bw = b ^ (k4 & 31);
      int base = k4 * 128;
      buf[base      + bw] = v[i*4+0];
      buf[base + 32 + bw] = v[i*4+1];
      buf[base + 64 + bw] = v[i*4+2];
      buf[base + 96 + bw] = v[i*4+3];
    }
  }
}

__device__ __forceinline__ float lds_at(const float* buf, int k, int b) {
  return buf[k * 32 + (b ^ ((k >> 2) & 31))];
}

// xw_t for THIS WG's 8 preact columns (col = 2w + (c2&1) + (c2>>1)*512),
// returned in a register per thread (t -> b2=t&31, c2=t>>5).
__device__ __forceinline__ float xw_compute(float* buf, const float* __restrict__ x,
                                            const float* __restrict__ W, int tt, int wg) {
  const int t = threadIdx.x;
  __syncthreads();                       // previous buf users done
  stage_rows(buf, x + (size_t)tt * DD, (size_t)TSTEPS * DD);
  __syncthreads();
  const int b = t & 31, s = t >> 5, k0 = s * 64;
  const int d0 = wg * 2;
  float acc[8] = {0.f,0.f,0.f,0.f,0.f,0.f,0.f,0.f};
  for (int k = k0; k < k0 + 64; k++) {
    float hv = lds_at(buf, k, b);
    const float* row = W + (size_t)k * KK4 + d0;
    float2 g0 = *(const float2*)(row);
    float2 g1 = *(const float2*)(row + 512);
    float2 g2 = *(const float2*)(row + 1024);
    float2 g3 = *(const float2*)(row + 1536);
    acc[0] += hv * g0.x; acc[1] += hv * g0.y;
    acc[2] += hv * g1.x; acc[3] += hv * g1.y;
    acc[4] += hv * g2.x; acc[5] += hv * g2.y;
    acc[6] += hv * g3.x; acc[7] += hv * g3.y;
  }
  __syncthreads();
#pragma unroll
  for (int cc = 0; cc < 8; cc++) buf[(cc * 8 + s) * 32 + b] = acc[cc];
  __syncthreads();
  const int b2 = t & 31, c2 = t >> 5;
  float sum = 0.f;
#pragma unroll
  for (int s2 = 0; s2 < 8; s2++) sum += buf[(c2 * 8 + s2) * 32 + b2];
  return sum;
}

__global__ __launch_bounds__(BD, 1) void attn_lstm_persistent(
    const float* __restrict__ x, const float* __restrict__ ctx,
    const float* __restrict__ W, const float* __restrict__ V,
    const float* __restrict__ U, const float* __restrict__ bias,
    const float* __restrict__ Wh, const float* __restrict__ Wc,
    const float* __restrict__ batt, const float* __restrict__ wprj,
    float* __restrict__ out, float* __restrict__ ws) {
  __shared__ float buf[16384];           // 64 KB
  __shared__ float aux[576];
  const int w = blockIdx.x;
  const int t = threadIdx.x;
  float* h    = ws + OFF_H;
  float* hatt = ws + OFF_HATT;
  float* wctx = ws + OFF_WCTX;
  float* Z    = ws + OFF_Z;
  float* att  = ws + OFF_ATT;
  int*   bar  = (int*)(ws + OFF_BAR);
  int gen = 0;

  const int b2g = t & 31, c2g = t >> 5;          // global thread->output mapping
  const int d0 = w * 2;
  const int mycol = d0 + (c2g & 1) + (c2g >> 1) * 512;
  const float bias_reg = bias[mycol];

  float xw_cur, xw_next = 0.f, hU_reg;
  float c_reg = 0.f;                              // t<64 threads own c[(t&31)][2w+(t>>5)]

  // ---------------- setup: att_ctx = context @ Wc + b_att (WG-local rows) ----------------
  {
    const int r0 = w * 16;
    for (int i = 0; i < 8; i++) {
      int idx4 = i * BD + t;
      int row = idx4 >> 7, c4 = idx4 & 127;
      ((float4*)buf)[idx4] = ((const float4*)(ctx + (size_t)(r0 + row) * DD))[c4];
    }
    __syncthreads();
    float accA[16], accB[16];
#pragma unroll
    for (int r = 0; r < 16; r++) { accA[r] = 0.f; accB[r] = 0.f; }
    const int a0 = t, a1 = t + 256;
    for (int cc = 0; cc < DD; cc++) {
      float w0 = Wc[(size_t)cc * DD + a0];
      float w1 = Wc[(size_t)cc * DD + a1];
#pragma unroll
      for (int r = 0; r < 16; r++) {
        float cv = buf[r * DD + cc];
        accA[r] += cv * w0; accB[r] += cv * w1;
      }
    }
    const float ba0 = batt[a0], ba1 = batt[a1];
    for (int r = 0; r < 16; r++) {
      att[(size_t)(r0 + r) * DD + a0] = accA[r] + ba0;   // normal: same WG reads it later
      att[(size_t)(r0 + r) * DD + a1] = accB[r] + ba1;
    }
  }
  xw_cur = xw_compute(buf, x, W, 0, w);
  gsync(bar, gen);

  // ---------------- recurrence ----------------
  for (int step = 0; step < TSTEPS; step++) {
    // ---- S1: every WG: hU (8 own cols -> reg) + hatt (2 cols, coherent store);
    //          fold in zeroing of wctx/Z for this step ----
    {
      if (t < 64) cstore(wctx + w * 64 + t, 0.f);
      if (w == 0 && t >= 64 && t < 96) cstore(Z + (t - 64), 0.f);
      stage_rows_coh(buf, h);
      __syncthreads();
      const int b = t & 31, s = t >> 5, k0 = s * 64;
      float acc[10];
#pragma unroll
      for (int i = 0; i < 10; i++) acc[i] = 0.f;
      for (int k = k0; k < k0 + 64; k++) {
        float hv = lds_at(buf, k, b);
        const float* row = U + (size_t)k * KK4 + d0;
        float2 g0 = *(const float2*)(row);
        float2 g1 = *(const float2*)(row + 512);
        float2 g2 = *(const float2*)(row + 1024);
        float2 g3 = *(const float2*)(row + 1536);
        float2 wh = *(const float2*)(Wh + (size_t)k * DD + d0);
        acc[0] += hv * g0.x; acc[1] += hv * g0.y;
        acc[2] += hv * g1.x; acc[3] += hv * g1.y;
        acc[4] += hv * g2.x; acc[5] += hv * g2.y;
        acc[6] += hv * g3.x; acc[7] += hv * g3.y;
        acc[8] += hv * wh.x; acc[9] += hv * wh.y;
      }
      __syncthreads();                   // staged h dead
#pragma unroll
      for (int cc = 0; cc < 10; cc++) buf[(cc * 8 + s) * 32 + b] = acc[cc];
      __syncthreads();
      float hu = 0.f;
#pragma unroll
      for (int s2 = 0; s2 < 8; s2++) hu += buf[(c2g * 8 + s2) * 32 + b2g];
      hU_reg = hu;
      if (t < 64) {
        const int b3 = t & 31, j = t >> 5;
        float sum = 0.f;
#pragma unroll
        for (int s2 = 0; s2 < 8; s2++) sum += buf[((8 + j) * 8 + s2) * 32 + b3];
        cstore(hatt + (size_t)b3 * DD + d0 + j, sum);
      }
    }
    gsync(bar, gen);

    // ---- S2: attention scores + unnormalized wctx; prefetch xw[t+1] ----
    {
      const int b = w >> 3, l0 = (w & 7) * 16;
      // stage hatt row b (coherent) into aux[0..512)
      aux[t]       = cload(hatt + (size_t)b * DD + t);
      aux[256 + t] = cload(hatt + (size_t)b * DD + 256 + t);
      __syncthreads();
      const int l = t >> 4, u = t & 15;
      const float* ar = att + (size_t)(b * LC + l0 + l) * DD;
      float p = 0.f;
#pragma unroll
      for (int j = 0; j < 8; j++) {
        int a4 = j * 16 + u;
        float4 av = ((const float4*)ar)[a4];
        float4 wv = ((const float4*)wprj)[a4];
        float hx = aux[a4*4], hy = aux[a4*4+1], hz = aux[a4*4+2], hw = aux[a4*4+3];
        p += ftanh(av.x + hx) * wv.x + ftanh(av.y + hy) * wv.y
           + ftanh(av.z + hz) * wv.z + ftanh(av.w + hw) * wv.w;
      }
      p += __shfl_xor(p, 8); p += __shfl_xor(p, 4);
      p += __shfl_xor(p, 2); p += __shfl_xor(p, 1);
      if (u == 0) {
        float uv = __expf(p);
        aux[512 + l] = uv;
        atomicAdd(&Z[b], uv);            // device-scope, coherent
      }
      __syncthreads();
      float s0 = 0.f, s1 = 0.f;
      const float* cr = ctx + (size_t)(b * LC + l0) * DD;
#pragma unroll 4
      for (int l2 = 0; l2 < 16; l2++) {
        float uv = aux[512 + l2];
        s0 += uv * cr[l2 * DD + t];
        s1 += uv * cr[l2 * DD + t + 256];
      }
      atomicAdd(&wctx[(size_t)b * DD + t], s0);
      atomicAdd(&wctx[(size_t)b * DD + t + 256], s1);
      if (step + 1 < TSTEPS) xw_next = xw_compute(buf, x, W, step + 1, w);
    }
    gsync(bar, gen);

    // ---- S3: preact = xw + hU + wctx@V + bias; gates; h/c update ----
    {
      stage_rows_coh(buf, wctx);                 // raw (unnormalized) wctx
      if (t < 32) aux[t] = cload(Z + t);
      __syncthreads();
      const int b = t & 31, s = t >> 5, k0 = s * 64;
      float acc[8] = {0.f,0.f,0.f,0.f,0.f,0.f,0.f,0.f};
      for (int k = k0; k < k0 + 64; k++) {
        float wv = lds_at(buf, k, b);
        const float* row = V + (size_t)k * KK4 + d0;
        float2 g0 = *(const float2*)(row);
        float2 g1 = *(const float2*)(row + 512);
        float2 g2 = *(const float2*)(row + 1024);
        float2 g3 = *(const float2*)(row + 1536);
        acc[0] += wv * g0.x; acc[1] += wv * g0.y;
        acc[2] += wv * g1.x; acc[3] += wv * g1.y;
        acc[4] += wv * g2.x; acc[5] += wv * g2.y;
        acc[6] += wv * g3.x; acc[7] += wv * g3.y;
      }
      const float rz = rcp_fast(aux[b]);
#pragma unroll
      for (int cc = 0; cc < 8; cc++) acc[cc] *= rz;
      __syncthreads();
#pragma unroll
      for (int cc = 0; cc < 8; cc++) buf[(cc * 8 + s) * 32 + b] = acc[cc];
      __syncthreads();
      {
        float sum = 0.f;
#pragma unroll
        for (int s2 = 0; s2 < 8; s2++) sum += buf[(c2g * 8 + s2) * 32 + b2g];
        sum += xw_cur + hU_reg + bias_reg;
        buf[2048 + c2g * 32 + b2g] = sum;        // disjoint from partials region
      }
      __syncthreads();
      if (t < 64) {
        const int b3 = t & 31, dd = t >> 5;
        const int d = d0 + dd;
        float pi = buf[2048 + (0 + dd) * 32 + b3];
        float pf = buf[2048 + (2 + dd) * 32 + b3];
        float po = buf[2048 + (4 + dd) * 32 + b3];
        float pg = buf[2048 + (6 + dd) * 32 + b3];
        float ig = fsig(pi), fg = fsig(pf), og = fsig(po), gg = ftanh(pg);
        float cn = fg * c_reg + ig * gg;
        c_reg = cn;
        float hn = og * ftanh(cn);
        cstore(h + (size_t)b3 * DD + d, hn);     // coherent: next S1 reads it
        out[(size_t)b3 * (TSTEPS * DD) + (size_t)step * DD + d] = hn;
      }
      xw_cur = xw_next;
    }
    gsync(bar, gen);
  }
}

extern "C" void kernel_launch(void* const* d_in, const int* in_sizes, int n_in,
                              void* d_out, int out_size, void* d_ws, size_t ws_size,
                              hipStream_t stream) {
  (void)in_sizes; (void)n_in; (void)out_size; (void)ws_size;
  const float* x    = (const float*)d_in[0];
  const float* ctx  = (const float*)d_in[1];
  const float* W    = (const float*)d_in[2];
  const float* V    = (const float*)d_in[3];
  const float* U    = (const float*)d_in[4];
  const float* b    = (const float*)d_in[5];
  const float* Wh   = (const float*)d_in[6];
  const float* Wc   = (const float*)d_in[7];
  const float* batt = (const float*)d_in[8];
  const float* wprj = (const float*)d_in[9];

  // zero h and the barrier counter (wctx/Z are zeroed in-kernel each step)
  hipMemsetAsync(d_ws, 0, 16384 * sizeof(float), stream);
  hipMemsetAsync((char*)d_ws + OFF_BAR * sizeof(float), 0, 64 * sizeof(int), stream);

  hipLaunchKernelGGL(attn_lstm_persistent, dim3(GD), dim3(BD), 0, stream,
                     x, ctx, W, V, U, b, Wh, Wc, batt, wprj,
                     (float*)d_out, (float*)d_ws);
}